// Round 3
// baseline (194.646 us; speedup 1.0000x reference)
//
#include <hip/hip_runtime.h>

// SpikeCountLayer: out[b,s,h,w] = #{t : in[b,t,h,w]==s}
// B=32 (derived), T=1024, H*W=1024, dim_s=32.
//
// R2: bit-plane popcount histogram. R1's compare-select update (24 VALU/elem,
// serialized through vcc/mask SGPRs) was latency-bound. Now: per group of 32
// t-values build 5 bit-planes (plane b, bit i = bit b of v_i), then count all
// 32 bins via shared-prefix AND tree + v_bcnt_u32_b32 accumulate:
// ~13 VALU/elem total, no compares, no mask-register chains.
// Loads unchanged: 256 B/wave contiguous, 16 outstanding per thread.

constexpr int T_DIM   = 1024;
constexpr int HW      = 1024;   // H*W
constexpr int DIM_S   = 32;
constexpr int PIX_PB  = 64;     // pixels per block
constexpr int TQ      = 8;      // t-slices (== waves per block)
constexpr int THREADS = PIX_PB * TQ;          // 512
constexpr int T_PER_THREAD = T_DIM / TQ;      // 128
constexpr int PLANE_CHUNKS = HW / PIX_PB;     // 16
constexpr int NGROUP  = T_PER_THREAD / 32;    // 4 groups of 32 t-values

__global__ __launch_bounds__(THREADS) void spike_hist_kernel(
    const int* __restrict__ in, int* __restrict__ out) {
    __shared__ int lds[DIM_S][THREADS];       // 64 KiB -> 2 blocks/CU

    const int tid  = threadIdx.x;
    const int blk  = blockIdx.x;              // [0, B*16)
    const int b    = blk >> 4;
    const int pix0 = (blk & (PLANE_CHUNKS - 1)) * PIX_PB;
    const int pix  = tid & (PIX_PB - 1);
    const int tq   = tid >> 6;

    const int* __restrict__ p = in
        + (size_t)b * (T_DIM * HW)
        + (size_t)(tq * T_PER_THREAD) * HW
        + pix0 + pix;

    int cnt[DIM_S];
    #pragma unroll
    for (int s = 0; s < DIM_S; ++s) cnt[s] = 0;

    #pragma unroll
    for (int g = 0; g < NGROUP; ++g) {
        unsigned p0 = 0, p1 = 0, p2 = 0, p3 = 0, p4 = 0;
        // two 16-load phases: 16 loads in flight, bounded VGPR pressure
        #pragma unroll
        for (int h = 0; h < 2; ++h) {
            unsigned v[16];
            #pragma unroll
            for (int i = 0; i < 16; ++i)
                v[i] = (unsigned)p[(size_t)(g * 32 + h * 16 + i) * HW];
            #pragma unroll
            for (int i = 0; i < 16; ++i) {
                const int sh = h * 16 + i;
                const unsigned x = v[i];
                p0 |= (x        & 1u) << sh;
                p1 |= ((x >> 1) & 1u) << sh;
                p2 |= ((x >> 2) & 1u) << sh;
                p3 |= ((x >> 3) & 1u) << sh;
                p4 |= ((x >> 4) & 1u) << sh;
            }
        }
        const unsigned n0 = ~p0, n1 = ~p1, n2 = ~p2, n3 = ~p3, n4 = ~p4;
        // a[k]: bits s1,s0 ; bq[j]: bits s3,s2 ; bin = s4*16 + j*4 + k
        const unsigned a[4]  = { n1 & n0, n1 & p0, p1 & n0, p1 & p0 };
        const unsigned bq[4] = { n3 & n2, n3 & p2, p3 & n2, p3 & p2 };
        #pragma unroll
        for (int j = 0; j < 4; ++j) {
            #pragma unroll
            for (int k = 0; k < 4; ++k) {
                const unsigned ab = bq[j] & a[k];
                cnt[j * 4 + k]      += __builtin_popcount(ab & n4);
                cnt[16 + j * 4 + k] += __builtin_popcount(ab & p4);
            }
        }
    }

    #pragma unroll
    for (int s = 0; s < DIM_S; ++s) lds[s][tid] = cnt[s];
    __syncthreads();

    // epilogue: out[b, s, pix0+opix] = sum over the 8 tq partials
    int* __restrict__ outb = out + (size_t)b * (DIM_S * HW) + pix0;
    #pragma unroll
    for (int r = 0; r < 4; ++r) {
        const int e    = r * THREADS + tid;   // [0, 2048)
        const int opix = e & (PIX_PB - 1);
        const int s    = e >> 6;              // wave-uniform
        int sum = 0;
        #pragma unroll
        for (int q = 0; q < TQ; ++q)
            sum += lds[s][q * PIX_PB + opix];
        outb[(size_t)s * HW + opix] = sum;    // coalesced 256 B/wave
    }
}

extern "C" void kernel_launch(void* const* d_in, const int* in_sizes, int n_in,
                              void* d_out, int out_size, void* d_ws, size_t ws_size,
                              hipStream_t stream) {
    const int* in = (const int*)d_in[0];
    int* out      = (int*)d_out;
    const int B   = in_sizes[0] / (T_DIM * HW);   // 32 for the reference setup
    const int grid = B * PLANE_CHUNKS;            // 512 blocks
    spike_hist_kernel<<<grid, THREADS, 0, stream>>>(in, out);
}

// Round 4
// 192.722 us; speedup vs baseline: 1.0100x; 1.0100x over previous
//
#include <hip/hip_runtime.h>

// SpikeCountLayer: out[b,s,h,w] = #{t : in[b,t,h,w]==s}
// B=32 (derived), T=1024, H*W=1024, dim_s=32.
//
// R3: load-path restructure. R1 vs R2 proved the kernel is load-bound, not
// VALU-bound (~68 cyc per wave-load-instr at dword width). Now each thread
// owns a 4-pixel quad and loads global_load_dwordx4 (16 B/lane): 4x fewer
// load instructions (512/CU vs 2048/CU), same bytes.
//  - grid 256 (1 block/CU): block = (b, 128-px chunk), 512 threads.
//  - thread = (sl = tid>>5 in [0,16), quad = tid&31); 64 t per thread.
//  - bitplane popcount histogram per pixel; counts byte-packed:
//    cw[c*8 + (s>>2)] byte (s&3) = count of bin s for pixel quad*4+c.
//    Max count 64 per thread-pixel < 255.
//  - epilogue: LDS [word][tid] (64 KiB), halfword-packed reduction over the
//    16 t-slices (sums <= 1024 fit u16), conflict-free (2-way only).

constexpr int T_DIM   = 1024;
constexpr int HW      = 1024;            // H*W
constexpr int DIM_S   = 32;
constexpr int PIX_PB  = 128;             // pixels per block
constexpr int QUADS   = PIX_PB / 4;      // 32 pixel-quads per block
constexpr int THREADS = 512;
constexpr int SLICES  = THREADS / QUADS; // 16 t-slices
constexpr int T_PER_THREAD = T_DIM / SLICES;  // 64
constexpr int CHUNKS  = HW / PIX_PB;     // 8

__global__ __launch_bounds__(THREADS) void spike_hist_kernel(
    const int* __restrict__ in, int* __restrict__ out) {
    __shared__ unsigned lds[32 * THREADS];   // 64 KiB: [cw-word m][tid]

    const int tid  = threadIdx.x;
    const int quad = tid & (QUADS - 1);
    const int sl   = tid >> 5;               // t-slice
    const int blk  = blockIdx.x;
    const int b    = blk >> 3;
    const int pix0 = (blk & (CHUNKS - 1)) * PIX_PB;

    const int* __restrict__ base = in
        + (size_t)b * (T_DIM * HW)
        + (size_t)(sl * T_PER_THREAD) * HW
        + pix0 + quad * 4;

    unsigned cw[32];                         // byte-packed counts, 4 px x 8 words
    #pragma unroll
    for (int m = 0; m < 32; ++m) cw[m] = 0u;

    #pragma unroll
    for (int g = 0; g < 2; ++g) {            // two 32-t groups
        unsigned pl[4][5];                   // per-px bit-planes
        #pragma unroll
        for (int c = 0; c < 4; ++c)
            #pragma unroll
            for (int j = 0; j < 5; ++j) pl[c][j] = 0u;

        #pragma unroll
        for (int ph = 0; ph < 4; ++ph) {     // 4 phases x 8 dwordx4 loads
            int4 v[8];
            #pragma unroll
            for (int i = 0; i < 8; ++i)
                v[i] = *(const int4*)(base + (size_t)(g * 32 + ph * 8 + i) * HW);
            #pragma unroll
            for (int i = 0; i < 8; ++i) {
                const int ti = ph * 8 + i;
                const unsigned xs[4] = { (unsigned)v[i].x, (unsigned)v[i].y,
                                         (unsigned)v[i].z, (unsigned)v[i].w };
                #pragma unroll
                for (int c = 0; c < 4; ++c) {
                    const unsigned x = xs[c];
                    #pragma unroll
                    for (int j = 0; j < 5; ++j)
                        pl[c][j] |= ((x >> j) & 1u) << ti;
                }
            }
        }

        #pragma unroll
        for (int c = 0; c < 4; ++c) {
            const unsigned p0 = pl[c][0], p1 = pl[c][1], p2 = pl[c][2],
                           p3 = pl[c][3], p4 = pl[c][4];
            const unsigned n0 = ~p0, n1 = ~p1, n2 = ~p2, n3 = ~p3, n4 = ~p4;
            const unsigned a[4]  = { n1 & n0, n1 & p0, p1 & n0, p1 & p0 };
            const unsigned bq[4] = { n3 & n2, n3 & p2, p3 & n2, p3 & p2 };
            #pragma unroll
            for (int j = 0; j < 4; ++j) {
                #pragma unroll
                for (int k = 0; k < 4; ++k) {
                    const unsigned ab = bq[j] & a[k];
                    // bin j*4+k (s4=0) -> word c*8+j, byte k
                    cw[c * 8 + j]     += (unsigned)__builtin_popcount(ab & n4) << (k * 8);
                    // bin 16+j*4+k    -> word c*8+4+j, byte k
                    cw[c * 8 + 4 + j] += (unsigned)__builtin_popcount(ab & p4) << (k * 8);
                }
            }
        }
    }

    #pragma unroll
    for (int m = 0; m < 32; ++m) lds[m * THREADS + tid] = cw[m];
    __syncthreads();

    // epilogue: 1024 dword-columns (c,w,quad); 2 per thread.
    // column sum over 16 slices, halfword-packed (max 16*64=1024 < 65536).
    int* __restrict__ outb = out + (size_t)b * (DIM_S * HW) + pix0;
    #pragma unroll
    for (int k = 0; k < 2; ++k) {
        const int col = k * THREADS + tid;   // [0, 1024)
        const int q   = col & 31;            // quad
        const int m   = col >> 5;            // c*8 + w
        const int c   = m >> 3;
        const int w   = m & 7;
        unsigned lo = 0u, hi = 0u;
        #pragma unroll
        for (int s2 = 0; s2 < SLICES; ++s2) {
            const unsigned x = lds[m * THREADS + s2 * 32 + q];  // bank=q: 2-way
            lo += x & 0x00FF00FFu;
            hi += (x >> 8) & 0x00FF00FFu;
        }
        // word w packs bins s(kb) = (w>>2)*16 + (w&3)*4 + kb at byte kb
        const int s_base = (w >> 2) * 16 + (w & 3) * 4;
        const int px     = q * 4 + c;
        int* __restrict__ op = outb + (size_t)s_base * HW + px;
        op[0 * HW] = (int)(lo & 0xFFFFu);
        op[1 * HW] = (int)(hi & 0xFFFFu);
        op[2 * HW] = (int)(lo >> 16);
        op[3 * HW] = (int)(hi >> 16);
    }
}

extern "C" void kernel_launch(void* const* d_in, const int* in_sizes, int n_in,
                              void* d_out, int out_size, void* d_ws, size_t ws_size,
                              hipStream_t stream) {
    const int* in = (const int*)d_in[0];
    int* out      = (int*)d_out;
    const int B   = in_sizes[0] / (T_DIM * HW);   // 32 for the reference setup
    const int grid = B * CHUNKS;                  // 256 blocks = 1/CU
    spike_hist_kernel<<<grid, THREADS, 0, stream>>>(in, out);
}